// Round 8
// baseline (186.822 us; speedup 1.0000x reference)
//
#include <hip/hip_runtime.h>

typedef __attribute__((ext_vector_type(8))) short short8;
typedef __attribute__((ext_vector_type(4))) short short4v;
typedef __attribute__((ext_vector_type(4))) float f32x4;

#define B_ROWS 4096
#define IN_STRIDE 8384
#define OUT_STRIDE 131

static __device__ __forceinline__ short f2bf(float f) {
  unsigned u = __float_as_uint(f);
  u = u + 0x7FFFu + ((u >> 16) & 1u);   // RNE
  return (short)(u >> 16);
}
static __device__ __forceinline__ float bf2f(short s) {
  return __uint_as_float(((unsigned)(unsigned short)s) << 16);
}
static __device__ __forceinline__ float fast_tanh(float x) {
  float e = __builtin_amdgcn_exp2f(x * 2.8853900817779268f);  // e^(2x)
  return 1.0f - 2.0f * __builtin_amdgcn_rcpf(e + 1.0f);
}

// ---------------- prep: fold weights, bf16 casts, transposes ----------------
__global__ __launch_bounds__(256) void prep_kernel(
    const float* __restrict__ W_emb, const float* __restrict__ b_emb,
    const float* __restrict__ Uq, const float* __restrict__ Ur,
    const float* __restrict__ W1p, const float* __restrict__ W1v,
    const float* __restrict__ W2p, const float* __restrict__ W2v,
    const float* __restrict__ b1p, const float* __restrict__ b1v,
    const float* __restrict__ b2p, const float* __restrict__ b2v,
    short* __restrict__ WembUq, short* __restrict__ WembUrT,
    short* __restrict__ Wemb16, float* __restrict__ bUq, float* __restrict__ bUr,
    float* __restrict__ b1cat, float* __restrict__ b2cat,
    short* __restrict__ W1T, short* __restrict__ W2T)
{
  const int blk = blockIdx.x, t = threadIdx.x;
  if (blk < 128) {
    const int d = blk & 63;
    const float* U = (blk < 64) ? Uq : Ur;
    float acc = 0.f;
    for (int k = 0; k < 256; ++k) acc += W_emb[d * 256 + k] * U[k * 256 + t];
    if (blk < 64) WembUq[d * 256 + t] = f2bf(acc);
    else          WembUrT[t * 64 + d] = f2bf(acc);   // [n][k] transposed
  } else if (blk == 128) {
    float aq = 0.f, ar = 0.f;
    for (int k = 0; k < 256; ++k) {
      float b = b_emb[k];
      aq += b * Uq[k * 256 + t];
      ar += b * Ur[k * 256 + t];
    }
    bUq[t] = aq; bUr[t] = ar;
  } else if (blk == 129) {
    b1cat[t] = b1p[t]; b1cat[256 + t] = b1v[t];
    b2cat[t] = b2p[t]; b2cat[256 + t] = b2v[t];
    for (int i = 0; i < 64; ++i) Wemb16[i * 256 + t] = f2bf(W_emb[i * 256 + t]);
  } else if (blk < 770) {
    const int e = (blk - 130) * 256 + t;        // [0, 163840)
    const int n = e / 320, k = e - n * 320;     // W1T[n][k], n<512, k<320
    const float v = (n < 256) ? W1p[k * 256 + n] : W1v[k * 256 + (n - 256)];
    W1T[e] = f2bf(v);
  } else {
    const int e = (blk - 770) * 256 + t;        // [0, 131072)
    const int n = e >> 8, k = e & 255;          // W2T[n][k], n<512, k<256
    const float v = (n < 256) ? W2p[k * 256 + n] : W2v[k * 256 + (n - 256)];
    W2T[e] = f2bf(v);
  }
}

// ---- fused attention: 1 WAVE = 1 row. ZERO barriers; 4 independent waves/block.
// Per-wave LDS slices only (same-wave RAW ordered by lgkmcnt). 4096 waves = 4/SIMD:
// if VGPR<=128 the whole grid is co-resident -> pure latency hiding, no coupling.
__global__ __launch_bounds__(256) void attn_kernel(
    const float* __restrict__ in, const short* __restrict__ BT,      // W_embUr^T [256][64]
    const short* __restrict__ WembUq, const short* __restrict__ Wemb16,
    const float* __restrict__ bUq, const float* __restrict__ bUr,
    const float* __restrict__ Ua, const float* __restrict__ b_emb,
    float* __restrict__ out, short* __restrict__ state)
{
  __shared__ float scr_lds[4][64];      // per-wave: osum, then obar
  __shared__ float qU_lds[4][256];      // per-wave qU
  __shared__ float logit_lds[4][128];   // per-wave logits

  const int t = threadIdx.x, wv = t >> 6, l = t & 63;
  const int q = l >> 4, r16 = l & 15;
  const int row = blockIdx.x * 4 + wv;
  const float* __restrict__ xrow = in + (size_t)row * IN_STRIDE;
  const float* __restrict__ others = xrow + 64;
  const float* __restrict__ maskp = xrow + 8256;

  float m0 = maskp[l], m1 = maskp[64 + l];
  float S = m0 + m1;
#pragma unroll
  for (int d = 1; d < 64; d <<= 1) S += __shfl_xor(S, d);

  // ---- phase B: all 8 m-tiles in this wave; masked bf16 A-frags + o_sum ----
  short8 afrag[8][2];
  float osA[8], osB[8];
#pragma unroll
  for (int j = 0; j < 8; ++j) { osA[j] = 0.f; osB[j] = 0.f; }
#pragma unroll
  for (int mt = 0; mt < 8; ++mt) {
    const int o = mt * 16 + r16;
    const float mk = (mt < 4) ? __shfl(m0, o) : __shfl(m1, o - 64);
    const float4* p = (const float4*)(others + o * 64 + q * 8);
    float4 a0 = p[0], a1 = p[1], c0 = p[8], c1 = p[9];
    float fa[8] = {a0.x, a0.y, a0.z, a0.w, a1.x, a1.y, a1.z, a1.w};
    float fb[8] = {c0.x, c0.y, c0.z, c0.w, c1.x, c1.y, c1.z, c1.w};
    short8 s0, s1;
#pragma unroll
    for (int j = 0; j < 8; ++j) {
      float va = fa[j] * mk, vb = fb[j] * mk;
      osA[j] += va; osB[j] += vb;
      s0[j] = f2bf(va); s1[j] = f2bf(vb);
    }
    afrag[mt][0] = s0; afrag[mt][1] = s1;
  }
#pragma unroll
  for (int d = 1; d < 16; d <<= 1) {
#pragma unroll
    for (int j = 0; j < 8; ++j) {
      osA[j] += __shfl_xor(osA[j], d);
      osB[j] += __shfl_xor(osB[j], d);
    }
  }
  if (r16 == 0) {
#pragma unroll
    for (int j = 0; j < 8; ++j) {
      scr_lds[wv][q * 8 + j] = osA[j];
      scr_lds[wv][q * 8 + 32 + j] = osB[j];
    }
  }

  // ---- phase C: qU cols [l*4, l*4+4): (o_sum @ WembUq + S*bUq)/(S+1e-5) + bUr ----
  {
    float ac0 = 0.f, ac1 = 0.f, ac2 = 0.f, ac3 = 0.f;
#pragma unroll 4
    for (int d = 0; d < 64; ++d) {
      const float osv = scr_lds[wv][d];
      short4v wq = *(const short4v*)&WembUq[d * 256 + l * 4];
      ac0 += osv * bf2f(wq[0]); ac1 += osv * bf2f(wq[1]);
      ac2 += osv * bf2f(wq[2]); ac3 += osv * bf2f(wq[3]);
    }
    const float rS = __builtin_amdgcn_rcpf(S + 1e-5f);
    const int j0 = l * 4;
    qU_lds[wv][j0 + 0] = (ac0 + S * bUq[j0 + 0]) * rS + bUr[j0 + 0];
    qU_lds[wv][j0 + 1] = (ac1 + S * bUq[j0 + 1]) * rS + bUr[j0 + 1];
    qU_lds[wv][j0 + 2] = (ac2 + S * bUq[j0 + 2]) * rS + bUr[j0 + 2];
    qU_lds[wv][j0 + 3] = (ac3 + S * bUq[j0 + 3]) * rS + bUr[j0 + 3];
  }

  // ---- phase D: 16 nt x 8 mt, MFMA C-init=qv, fused tanh + Ua-dot ----
  f32x4 lp[8];
#pragma unroll
  for (int mt = 0; mt < 8; ++mt) lp[mt] = (f32x4){0.f, 0.f, 0.f, 0.f};
#pragma unroll 2
  for (int nt = 0; nt < 16; ++nt) {
    const int col = nt * 16 + r16;
    const float qv = qU_lds[wv][col];
    const float uav = Ua[col];
    const short8 bf0 = *(const short8*)&BT[col * 64 + q * 8];
    const short8 bf1 = *(const short8*)&BT[col * 64 + 32 + q * 8];
#pragma unroll
    for (int mt = 0; mt < 8; ++mt) {
      f32x4 acc = {qv, qv, qv, qv};
      acc = __builtin_amdgcn_mfma_f32_16x16x32_bf16(afrag[mt][0], bf0, acc, 0, 0, 0);
      acc = __builtin_amdgcn_mfma_f32_16x16x32_bf16(afrag[mt][1], bf1, acc, 0, 0, 0);
#pragma unroll
      for (int rr = 0; rr < 4; ++rr) {
        lp[mt][rr] += uav * fast_tanh(acc[rr]);
      }
    }
  }
  // reduce logit partials over the 16 lanes of each quarter; mask; store
#pragma unroll
  for (int mt = 0; mt < 8; ++mt) {
#pragma unroll
    for (int rr = 0; rr < 4; ++rr) {
      float v = lp[mt][rr];
      v += __shfl_xor(v, 1); v += __shfl_xor(v, 2);
      v += __shfl_xor(v, 4); v += __shfl_xor(v, 8);
      const int n = mt * 16 + q * 4 + rr;
      const float mv = (mt < 4) ? __shfl(m0, n) : __shfl(m1, n - 64);
      if (mv == 0.f) v = -1e9f;
      if (r16 == 0) logit_lds[wv][n] = v;
    }
  }

  // ---- softmax over 128 logits (wave-local) ----
  float a0, a1;
  {
    float l0 = logit_lds[wv][l], l1 = logit_lds[wv][64 + l];
    float mx = fmaxf(l0, l1);
#pragma unroll
    for (int d = 1; d < 64; d <<= 1) mx = fmaxf(mx, __shfl_xor(mx, d));
    float e0 = __builtin_amdgcn_exp2f((l0 - mx) * 1.4426950408889634f);
    float e1 = __builtin_amdgcn_exp2f((l1 - mx) * 1.4426950408889634f);
    float s = e0 + e1;
#pragma unroll
    for (int d = 1; d < 64; d <<= 1) s += __shfl_xor(s, d);
    float rs = __builtin_amdgcn_rcpf(s);
    a0 = e0 * rs; a1 = e1 * rs;
    float* __restrict__ orow = out + (size_t)row * OUT_STRIDE;
    orow[3 + l] = a0;
    orow[3 + 64 + l] = a1;
  }

  // ---- phase G: o_bar = sum_n attn[n]*maskedOthers[n] (wave-local) ----
  {
    float ob[16];
#pragma unroll
    for (int j = 0; j < 16; ++j) ob[j] = 0.f;
#pragma unroll
    for (int mt = 0; mt < 8; ++mt) {
      const int o = mt * 16 + r16;
      const float av = (mt < 4) ? __shfl(a0, o) : __shfl(a1, o - 64);
      const short8 f0 = afrag[mt][0], f1 = afrag[mt][1];
#pragma unroll
      for (int j = 0; j < 8; ++j) {
        ob[j] += av * bf2f(f0[j]);
        ob[8 + j] += av * bf2f(f1[j]);
      }
    }
#pragma unroll
    for (int d = 1; d < 16; d <<= 1) {
#pragma unroll
      for (int j = 0; j < 16; ++j) ob[j] += __shfl_xor(ob[j], d);
    }
    if (r16 == 0) {
#pragma unroll
      for (int j = 0; j < 8; ++j) {
        scr_lds[wv][q * 8 + j] = ob[j];          // reuse: obar now
        scr_lds[wv][q * 8 + 32 + j] = ob[8 + j];
      }
    }
  }

  // ---- phase H: pooled cols [l*4, l*4+4); state = [obs[0:64], pooled] bf16 ----
  {
    float p0 = 0.f, p1 = 0.f, p2 = 0.f, p3 = 0.f;
#pragma unroll 4
    for (int d = 0; d < 64; ++d) {
      const float obv = scr_lds[wv][d];
      short4v wm = *(const short4v*)&Wemb16[d * 256 + l * 4];
      p0 += obv * bf2f(wm[0]); p1 += obv * bf2f(wm[1]);
      p2 += obv * bf2f(wm[2]); p3 += obv * bf2f(wm[3]);
    }
    short* __restrict__ srow = state + (size_t)row * 320;
    const int j0 = l * 4;
    srow[64 + j0 + 0] = f2bf(p0 + b_emb[j0 + 0]);
    srow[64 + j0 + 1] = f2bf(p1 + b_emb[j0 + 1]);
    srow[64 + j0 + 2] = f2bf(p2 + b_emb[j0 + 2]);
    srow[64 + j0 + 3] = f2bf(p3 + b_emb[j0 + 3]);
    srow[l] = f2bf(xrow[l]);
  }
}

// ---------------- MLP GEMM: C = tanh(A @ BT^T + bias), BM=64 BN=128, bf16 ----------------
__global__ __launch_bounds__(256) void mlp_gemm(
    const short* __restrict__ A, int lda, const short* __restrict__ BT,
    const float* __restrict__ bias, short* __restrict__ C, int ldc,
    int K, int split)
{
  __shared__ short Alds[64 * 32];
  __shared__ short Blds[128 * 32];
  const int t = threadIdx.x, l = t & 63, wid = t >> 6;
  const int bm = blockIdx.x, bn = blockIdx.y;
  const int acol0 = (split && bn >= ((int)gridDim.y >> 1)) ? K : 0;
  const int wm = wid >> 1, wn = wid & 1;          // wave tile 32x64
  const int q = l >> 4, r16 = l & 15;
  const f32x4 fzero = {0.f, 0.f, 0.f, 0.f};
  f32x4 acc[2][4];
#pragma unroll
  for (int fm = 0; fm < 2; ++fm)
#pragma unroll
    for (int fn = 0; fn < 4; ++fn) acc[fm][fn] = fzero;

  for (int kt = 0; kt < K; kt += 32) {
    {
      const int rrow = t >> 2, c = t & 3;          // A: 64 rows x 4 chunks
      int4 va = *(const int4*)&A[(size_t)(bm * 64 + rrow) * lda + acol0 + kt + c * 8];
      *(int4*)&Alds[rrow * 32 + ((c ^ (rrow & 3)) << 3)] = va;
#pragma unroll
      for (int e = 0; e < 2; ++e) {
        const int ei = t + e * 256;                // B: 128 rows x 4 chunks
        const int br = ei >> 2, bc = ei & 3;
        int4 vb = *(const int4*)&BT[(size_t)(bn * 128 + br) * K + kt + bc * 8];
        *(int4*)&Blds[br * 32 + ((bc ^ (br & 3)) << 3)] = vb;
      }
    }
    __syncthreads();
    short8 af[2], bf[4];
#pragma unroll
    for (int fm = 0; fm < 2; ++fm) {
      const int ar = wm * 32 + fm * 16 + r16;
      af[fm] = *(const short8*)&Alds[ar * 32 + ((q ^ (ar & 3)) << 3)];
    }
#pragma unroll
    for (int fn = 0; fn < 4; ++fn) {
      const int br = wn * 64 + fn * 16 + r16;
      bf[fn] = *(const short8*)&Blds[br * 32 + ((q ^ (br & 3)) << 3)];
    }
#pragma unroll
    for (int fm = 0; fm < 2; ++fm)
#pragma unroll
      for (int fn = 0; fn < 4; ++fn)
        acc[fm][fn] = __builtin_amdgcn_mfma_f32_16x16x32_bf16(af[fm], bf[fn], acc[fm][fn], 0, 0, 0);
    __syncthreads();
  }

#pragma unroll
  for (int fn = 0; fn < 4; ++fn) {
    const int col = bn * 128 + wn * 64 + fn * 16 + r16;
    const float bv = bias[col];
#pragma unroll
    for (int fm = 0; fm < 2; ++fm) {
#pragma unroll
      for (int rr = 0; rr < 4; ++rr) {
        const int crow = bm * 64 + wm * 32 + fm * 16 + q * 4 + rr;
        C[(size_t)crow * ldc + col] = f2bf(fast_tanh(acc[fm][fn][rr] + bv));
      }
    }
  }
}

// ---------------- head: value + action from H2 ----------------
__global__ __launch_bounds__(256) void head_kernel(
    const short* __restrict__ H2, const float* __restrict__ W3p,
    const float* __restrict__ b3p, const float* __restrict__ W3v,
    const float* __restrict__ b3v, float* __restrict__ out)
{
  const int t = threadIdx.x, w = t >> 6, l = t & 63;
  const int row = blockIdx.x * 4 + w;
  const short* __restrict__ h = H2 + (size_t)row * 512;
  float vp0 = 0.f, vp1 = 0.f, vv = 0.f;
#pragma unroll
  for (int i = 0; i < 4; ++i) {
    const int k = i * 64 + l;
    const float hp = bf2f(h[k]);
    const float hv = bf2f(h[256 + k]);
    vp0 += hp * W3p[k * 4 + 0];
    vp1 += hp * W3p[k * 4 + 1];
    vv += hv * W3v[k];
  }
#pragma unroll
  for (int d = 1; d < 64; d <<= 1) {
    vp0 += __shfl_xor(vp0, d);
    vp1 += __shfl_xor(vp1, d);
    vv += __shfl_xor(vv, d);
  }
  if (l == 0) {
    float* __restrict__ orow = out + (size_t)row * OUT_STRIDE;
    orow[0] = vv + b3v[0];
    orow[1] = fast_tanh(vp0 + b3p[0]);
    orow[2] = fast_tanh(vp1 + b3p[1]);
  }
}

extern "C" void kernel_launch(void* const* d_in, const int* in_sizes, int n_in,
                              void* d_out, int out_size, void* d_ws, size_t ws_size,
                              hipStream_t stream) {
  (void)in_sizes; (void)n_in; (void)out_size; (void)ws_size;
  const float* inp   = (const float*)d_in[0];
  const float* W_emb = (const float*)d_in[1];
  const float* b_emb = (const float*)d_in[2];
  const float* Uq    = (const float*)d_in[3];
  const float* Ur    = (const float*)d_in[4];
  const float* Ua    = (const float*)d_in[5];
  const float* W1p   = (const float*)d_in[6];
  const float* b1p   = (const float*)d_in[7];
  const float* W2p   = (const float*)d_in[8];
  const float* b2p   = (const float*)d_in[9];
  const float* W3p   = (const float*)d_in[10];
  const float* b3p   = (const float*)d_in[11];
  const float* W1v   = (const float*)d_in[12];
  const float* b1v   = (const float*)d_in[13];
  const float* W2v   = (const float*)d_in[14];
  const float* b2v   = (const float*)d_in[15];
  const float* W3v   = (const float*)d_in[16];
  const float* b3v   = (const float*)d_in[17];

  char* ws = (char*)d_ws;
  short* WembUq  = (short*)(ws + 0);        // 64x256 bf16
  short* WembUrT = (short*)(ws + 32768);    // 256x64 bf16 (transposed)
  short* Wemb16  = (short*)(ws + 65536);    // 64x256 bf16
  float* bUq     = (float*)(ws + 98304);    // 256 f32
  float* bUr     = (float*)(ws + 99328);    // 256 f32
  float* b1cat   = (float*)(ws + 100352);   // 512 f32
  float* b2cat   = (float*)(ws + 102400);   // 512 f32
  short* W1T     = (short*)(ws + 104448);   // 512x320 bf16
  short* W2T     = (short*)(ws + 432128);   // 512x256 bf16
  short* state   = (short*)(ws + 694272);   // 4096x320 bf16
  short* H1      = (short*)(ws + 3315712);  // 4096x512 bf16
  short* H2      = (short*)(ws + 7510016);  // 4096x512 bf16

  prep_kernel<<<dim3(1282), dim3(256), 0, stream>>>(
      W_emb, b_emb, Uq, Ur, W1p, W1v, W2p, W2v, b1p, b1v, b2p, b2v,
      WembUq, WembUrT, Wemb16, bUq, bUr, b1cat, b2cat, W1T, W2T);

  attn_kernel<<<dim3(1024), dim3(256), 0, stream>>>(
      inp, WembUrT, WembUq, Wemb16, bUq, bUr, Ua, b_emb, (float*)d_out, state);

  mlp_gemm<<<dim3(64, 4), dim3(256), 0, stream>>>(state, 320, W1T, b1cat, H1, 512, 320, 0);
  mlp_gemm<<<dim3(64, 4), dim3(256), 0, stream>>>(H1, 512, W2T, b2cat, H2, 512, 256, 1);

  head_kernel<<<dim3(1024), dim3(256), 0, stream>>>(H2, W3p, b3p, W3v, b3v, (float*)d_out);
}

// Round 9
// 142.896 us; speedup vs baseline: 1.3074x; 1.3074x over previous
//
#include <hip/hip_runtime.h>

typedef __attribute__((ext_vector_type(8))) short short8;
typedef __attribute__((ext_vector_type(4))) float f32x4;

#define B_ROWS 4096
#define IN_STRIDE 8384
#define OUT_STRIDE 131
#define SC 2.8853900817779268f   // 2*log2(e)

static __device__ __forceinline__ short f2bf(float f) {
  unsigned u = __float_as_uint(f);
  u = u + 0x7FFFu + ((u >> 16) & 1u);   // RNE
  return (short)(u >> 16);
}
static __device__ __forceinline__ float bf2f(short s) {
  return __uint_as_float(((unsigned)(unsigned short)s) << 16);
}
static __device__ __forceinline__ float fast_tanh(float x) {
  float e = __builtin_amdgcn_exp2f(x * SC);  // e^(2x)
  return 1.0f - 2.0f * __builtin_amdgcn_rcpf(e + 1.0f);
}
static __device__ __forceinline__ unsigned cvt_pk_bf16(float lo, float hi) {
  unsigned u;
  asm("v_cvt_pk_bf16_f32 %0, %1, %2" : "=v"(u) : "v"(lo), "v"(hi));
  return u;
}

// ---------------- prep: fold weights, scale folds, casts, transposes ----------------
__global__ __launch_bounds__(256) void prep_kernel(
    const float* __restrict__ W_emb, const float* __restrict__ b_emb,
    const float* __restrict__ Uq, const float* __restrict__ Ur,
    const float* __restrict__ Ua,
    const float* __restrict__ W1p, const float* __restrict__ W1v,
    const float* __restrict__ W2p, const float* __restrict__ W2v,
    const float* __restrict__ b1p, const float* __restrict__ b1v,
    const float* __restrict__ b2p, const float* __restrict__ b2v,
    float* __restrict__ WqF, short* __restrict__ WembUrT,
    float* __restrict__ WembF, float* __restrict__ bUq2, float* __restrict__ bUr2,
    float* __restrict__ Ua2, float* __restrict__ sumUa,
    float* __restrict__ b1cat, float* __restrict__ b2cat,
    short* __restrict__ W1T, short* __restrict__ W2T)
{
  __shared__ float red[256];
  const int blk = blockIdx.x, t = threadIdx.x;
  if (blk < 128) {
    const int d = blk & 63;
    const float* U = (blk < 64) ? Uq : Ur;
    float acc = 0.f;
    for (int k = 0; k < 256; ++k) acc += W_emb[d * 256 + k] * U[k * 256 + t];
    if (blk < 64) WqF[d * 256 + t] = acc;            // f32, true scale
    else          WembUrT[t * 64 + d] = f2bf(acc);   // bf16 [n][k] transposed
  } else if (blk == 128) {
    float aq = 0.f, ar = 0.f;
    for (int k = 0; k < 256; ++k) {
      float b = b_emb[k];
      aq += b * Uq[k * 256 + t];
      ar += b * Ur[k * 256 + t];
    }
    bUq2[t] = SC * aq; bUr2[t] = SC * ar;            // pre-scaled by 2log2e
    float ua = Ua[t];
    Ua2[t] = -2.f * ua;
    red[t] = ua; __syncthreads();
    for (int s = 128; s > 0; s >>= 1) { if (t < s) red[t] += red[t + s]; __syncthreads(); }
    if (t == 0) sumUa[0] = red[0];
  } else if (blk == 129) {
    b1cat[t] = b1p[t]; b1cat[256 + t] = b1v[t];
    b2cat[t] = b2p[t]; b2cat[256 + t] = b2v[t];
    const float inv = 1.0f / SC;
    for (int i = 0; i < 64; ++i) WembF[i * 256 + t] = W_emb[i * 256 + t] * inv;
  } else if (blk < 770) {
    const int e = (blk - 130) * 256 + t;        // [0, 163840)
    const int n = e / 320, k = e - n * 320;     // W1T[n][k], n<512, k<320
    const float v = (n < 256) ? W1p[k * 256 + n] : W1v[k * 256 + (n - 256)];
    W1T[e] = f2bf(v);
  } else {
    const int e = (blk - 770) * 256 + t;        // [0, 131072)
    const int n = e >> 8, k = e & 255;          // W2T[n][k], n<512, k<256
    const float v = (n < 256) ? W2p[k * 256 + n] : W2v[k * 256 + (n - 256)];
    W2T[e] = f2bf(v);
  }
}

// ---- fused attention: 1 block (4 waves, 256 thr) = 1 row (R3 structure + instr diet) ----
// A-frags and qU pre-scaled by 2log2e -> exp2 eats MFMA output directly.
// logits = sumUa + sum_j Ua2[j]*rcp(exp2(acc)+1). Tables for C/H phases in f32.
__global__ __launch_bounds__(256) void attn_kernel(
    const float* __restrict__ in, const short* __restrict__ BT,      // W_embUr^T [256][64] bf16
    const float* __restrict__ WqF, const float* __restrict__ WembF,
    const float* __restrict__ bUq2, const float* __restrict__ bUr2,
    const float* __restrict__ Ua2, const float* __restrict__ sumUa,
    const float* __restrict__ b_emb,
    float* __restrict__ out, short* __restrict__ state)
{
  __shared__ short Blds[256 * 64];      // 32768B, swizzled: chunk c of row n at c^(n&7)
  __shared__ float red_p[4][64];        // 1024B (osum partials, then obar partials)
  __shared__ float red_tot[64];         // 256B
  __shared__ float qU_lds[256];         // 1024B (scaled by SC)
  __shared__ float logit_lds[128];      // 512B

  const int t = threadIdx.x, w = t >> 6, l = t & 63;
  const int q = l >> 4, r16 = l & 15;
  const int row = blockIdx.x;
  const float* __restrict__ xrow = in + (size_t)row * IN_STRIDE;
  const float* __restrict__ others = xrow + 64;
  const float* __restrict__ maskp = xrow + 8256;

  // ---- issue row loads early; stage B to LDS ----
  float m0 = maskp[l], m1 = maskp[64 + l];
  float4 pv[2][4];
#pragma unroll
  for (int ml = 0; ml < 2; ++ml) {
    const int gr = (2 * w + ml) * 16 + r16;
    const float4* p = (const float4*)(others + gr * 64 + q * 8);
    pv[ml][0] = p[0]; pv[ml][1] = p[1]; pv[ml][2] = p[8]; pv[ml][3] = p[9];
  }
  {
    const int4* src = (const int4*)BT;
#pragma unroll
    for (int it = 0; it < 8; ++it) {
      int cl = it * 256 + t;                 // chunk linear [0,2048)
      int n = cl >> 3, c = cl & 7;
      int4 v = src[cl];
      *(int4*)&Blds[n * 64 + ((c ^ (n & 7)) << 3)] = v;
    }
  }

  float S = m0 + m1;
#pragma unroll
  for (int d = 1; d < 64; d <<= 1) S += __shfl_xor(S, d);

  // ---- phase B: masked+SCALED bf16 A-frags (cvt_pk) + o_sum partials ----
  short8 afrag[2][2];
  float osA[8], osB[8];
#pragma unroll
  for (int j = 0; j < 8; ++j) { osA[j] = 0.f; osB[j] = 0.f; }
#pragma unroll
  for (int ml = 0; ml < 2; ++ml) {
    const int midx = 32 * w + 16 * ml + r16;
    const float mk = ((w < 2) ? __shfl(m0, midx) : __shfl(m1, midx & 63)) * SC;
    float fa[8] = {pv[ml][0].x, pv[ml][0].y, pv[ml][0].z, pv[ml][0].w,
                   pv[ml][1].x, pv[ml][1].y, pv[ml][1].z, pv[ml][1].w};
    float fb[8] = {pv[ml][2].x, pv[ml][2].y, pv[ml][2].z, pv[ml][2].w,
                   pv[ml][3].x, pv[ml][3].y, pv[ml][3].z, pv[ml][3].w};
    short8 s0, s1;
#pragma unroll
    for (int j = 0; j < 4; ++j) {
      float a_lo = fa[2 * j] * mk, a_hi = fa[2 * j + 1] * mk;
      float b_lo = fb[2 * j] * mk, b_hi = fb[2 * j + 1] * mk;
      osA[2 * j] += a_lo; osA[2 * j + 1] += a_hi;
      osB[2 * j] += b_lo; osB[2 * j + 1] += b_hi;
      ((unsigned*)&s0)[j] = cvt_pk_bf16(a_lo, a_hi);
      ((unsigned*)&s1)[j] = cvt_pk_bf16(b_lo, b_hi);
    }
    afrag[ml][0] = s0; afrag[ml][1] = s1;
  }
#pragma unroll
  for (int d = 1; d < 16; d <<= 1) {
#pragma unroll
    for (int j = 0; j < 8; ++j) {
      osA[j] += __shfl_xor(osA[j], d);
      osB[j] += __shfl_xor(osB[j], d);
    }
  }
  if (r16 == 0) {
#pragma unroll
    for (int j = 0; j < 8; ++j) {
      red_p[w][q * 8 + j] = osA[j];        // scaled o_sum (SC folded)
      red_p[w][q * 8 + 32 + j] = osB[j];
    }
  }
  __syncthreads();

  if (t < 64) red_tot[t] = red_p[0][t] + red_p[1][t] + red_p[2][t] + red_p[3][t];
  __syncthreads();

  // ---- phase C: qU_s[t] = (osum_s @ WqF + S*bUq2)/(S+1e-5) + bUr2 ----
  {
    float ac0 = 0.f, ac1 = 0.f, ac2 = 0.f, ac3 = 0.f;
#pragma unroll 2
    for (int d = 0; d < 64; d += 4) {
      ac0 = fmaf(red_tot[d + 0], WqF[(d + 0) * 256 + t], ac0);
      ac1 = fmaf(red_tot[d + 1], WqF[(d + 1) * 256 + t], ac1);
      ac2 = fmaf(red_tot[d + 2], WqF[(d + 2) * 256 + t], ac2);
      ac3 = fmaf(red_tot[d + 3], WqF[(d + 3) * 256 + t], ac3);
    }
    const float accq = (ac0 + ac1) + (ac2 + ac3);
    const float rS = __builtin_amdgcn_rcpf(S + 1e-5f);
    qU_lds[t] = fmaf(S, bUq2[t], accq) * rS + bUr2[t];
  }
  __syncthreads();

  // ---- phase D: MFMA (C-init = qv_s), exp2+rcp+fma only per element ----
  const float sU = sumUa[0];
  f32x4 lp[2];
  lp[0] = (f32x4){0.f, 0.f, 0.f, 0.f};
  lp[1] = (f32x4){0.f, 0.f, 0.f, 0.f};
  for (int nt = 0; nt < 16; ++nt) {
    const int col = nt * 16 + r16;
    const float qv = qU_lds[col];
    const float ua2v = Ua2[col];
    const int sw = col & 7;
    const short8 bf0 = *(const short8*)&Blds[col * 64 + (((q) ^ sw) << 3)];
    const short8 bf1 = *(const short8*)&Blds[col * 64 + (((q + 4) ^ sw) << 3)];
#pragma unroll
    for (int ml = 0; ml < 2; ++ml) {
      f32x4 acc = {qv, qv, qv, qv};
      acc = __builtin_amdgcn_mfma_f32_16x16x32_bf16(afrag[ml][0], bf0, acc, 0, 0, 0);
      acc = __builtin_amdgcn_mfma_f32_16x16x32_bf16(afrag[ml][1], bf1, acc, 0, 0, 0);
#pragma unroll
      for (int rr = 0; rr < 4; ++rr) {
        float e = __builtin_amdgcn_exp2f(acc[rr]);           // exp2(2x*log2e)=e^{2x}
        float r = __builtin_amdgcn_rcpf(e + 1.0f);
        lp[ml][rr] = fmaf(ua2v, r, lp[ml][rr]);              // sum of -2*Ua*r
      }
    }
  }
#pragma unroll
  for (int ml = 0; ml < 2; ++ml) {
#pragma unroll
    for (int rr = 0; rr < 4; ++rr) {
      float v = lp[ml][rr];
      v += __shfl_xor(v, 1); v += __shfl_xor(v, 2);
      v += __shfl_xor(v, 4); v += __shfl_xor(v, 8);
      const int n = (2 * w + ml) * 16 + q * 4 + rr;
      const float mv = (w < 2) ? __shfl(m0, n) : __shfl(m1, n - 64);
      float lg = sU + v;                                     // sumUa - 2*sum(Ua*r)
      if (mv == 0.f) lg = -1e9f;
      if (r16 == 0) logit_lds[n] = lg;
    }
  }
  __syncthreads();

  // ---- softmax over 128 logits (wave-redundant) ----
  float a0, a1;
  {
    float l0 = logit_lds[l], l1 = logit_lds[64 + l];
    float mx = fmaxf(l0, l1);
#pragma unroll
    for (int d = 1; d < 64; d <<= 1) mx = fmaxf(mx, __shfl_xor(mx, d));
    float e0 = __builtin_amdgcn_exp2f((l0 - mx) * 1.4426950408889634f);
    float e1 = __builtin_amdgcn_exp2f((l1 - mx) * 1.4426950408889634f);
    float s = e0 + e1;
#pragma unroll
    for (int d = 1; d < 64; d <<= 1) s += __shfl_xor(s, d);
    float rs = __builtin_amdgcn_rcpf(s);
    a0 = e0 * rs; a1 = e1 * rs;
    float* __restrict__ orow = out + (size_t)row * OUT_STRIDE;
    if (w == 0) orow[3 + l] = a0;
    if (w == 1) orow[3 + 64 + l] = a1;
  }

  // ---- phase G: o_bar partials (scaled afrag -> obar_s; unscale folded in WembF) ----
  {
    float ob[16];
#pragma unroll
    for (int j = 0; j < 16; ++j) ob[j] = 0.f;
#pragma unroll
    for (int ml = 0; ml < 2; ++ml) {
      const int idx = 32 * w + 16 * ml + r16;
      const float av = (w < 2) ? __shfl(a0, idx) : __shfl(a1, idx & 63);
      const short8 f0 = afrag[ml][0], f1 = afrag[ml][1];
#pragma unroll
      for (int j = 0; j < 8; ++j) {
        ob[j] = fmaf(av, bf2f(f0[j]), ob[j]);
        ob[8 + j] = fmaf(av, bf2f(f1[j]), ob[8 + j]);
      }
    }
#pragma unroll
    for (int d = 1; d < 16; d <<= 1) {
#pragma unroll
      for (int j = 0; j < 16; ++j) ob[j] += __shfl_xor(ob[j], d);
    }
    __syncthreads();               // red_p free for reuse
    if (r16 == 0) {
#pragma unroll
      for (int j = 0; j < 8; ++j) {
        red_p[w][q * 8 + j] = ob[j];
        red_p[w][q * 8 + 32 + j] = ob[8 + j];
      }
    }
  }
  __syncthreads();
  if (t < 64) red_tot[t] = red_p[0][t] + red_p[1][t] + red_p[2][t] + red_p[3][t];
  __syncthreads();

  // ---- phase H: pooled col t via f32 WembF (1/SC folded); state bf16 ----
  {
    float ac0 = 0.f, ac1 = 0.f, ac2 = 0.f, ac3 = 0.f;
#pragma unroll 2
    for (int d = 0; d < 64; d += 4) {
      ac0 = fmaf(red_tot[d + 0], WembF[(d + 0) * 256 + t], ac0);
      ac1 = fmaf(red_tot[d + 1], WembF[(d + 1) * 256 + t], ac1);
      ac2 = fmaf(red_tot[d + 2], WembF[(d + 2) * 256 + t], ac2);
      ac3 = fmaf(red_tot[d + 3], WembF[(d + 3) * 256 + t], ac3);
    }
    const float p = (ac0 + ac1) + (ac2 + ac3) + b_emb[t];
    short* __restrict__ srow = state + (size_t)row * 320;
    srow[64 + t] = f2bf(p);
    if (t < 64) srow[t] = f2bf(xrow[t]);
  }
}

// ---------------- MLP GEMM: C = tanh(A @ BT^T + bias), BM=64 BN=128, bf16 ----------------
__global__ __launch_bounds__(256) void mlp_gemm(
    const short* __restrict__ A, int lda, const short* __restrict__ BT,
    const float* __restrict__ bias, short* __restrict__ C, int ldc,
    int K, int split)
{
  __shared__ short Alds[64 * 32];
  __shared__ short Blds[128 * 32];
  const int t = threadIdx.x, l = t & 63, wid = t >> 6;
  const int bm = blockIdx.x, bn = blockIdx.y;
  const int acol0 = (split && bn >= ((int)gridDim.y >> 1)) ? K : 0;
  const int wm = wid >> 1, wn = wid & 1;          // wave tile 32x64
  const int q = l >> 4, r16 = l & 15;
  const f32x4 fzero = {0.f, 0.f, 0.f, 0.f};
  f32x4 acc[2][4];
#pragma unroll
  for (int fm = 0; fm < 2; ++fm)
#pragma unroll
    for (int fn = 0; fn < 4; ++fn) acc[fm][fn] = fzero;

  for (int kt = 0; kt < K; kt += 32) {
    {
      const int rrow = t >> 2, c = t & 3;          // A: 64 rows x 4 chunks
      int4 va = *(const int4*)&A[(size_t)(bm * 64 + rrow) * lda + acol0 + kt + c * 8];
      *(int4*)&Alds[rrow * 32 + ((c ^ (rrow & 3)) << 3)] = va;
#pragma unroll
      for (int e = 0; e < 2; ++e) {
        const int ei = t + e * 256;                // B: 128 rows x 4 chunks
        const int br = ei >> 2, bc = ei & 3;
        int4 vb = *(const int4*)&BT[(size_t)(bn * 128 + br) * K + kt + bc * 8];
        *(int4*)&Blds[br * 32 + ((bc ^ (br & 3)) << 3)] = vb;
      }
    }
    __syncthreads();
    short8 af[2], bf[4];
#pragma unroll
    for (int fm = 0; fm < 2; ++fm) {
      const int ar = wm * 32 + fm * 16 + r16;
      af[fm] = *(const short8*)&Alds[ar * 32 + ((q ^ (ar & 3)) << 3)];
    }
#pragma unroll
    for (int fn = 0; fn < 4; ++fn) {
      const int br = wn * 64 + fn * 16 + r16;
      bf[fn] = *(const short8*)&Blds[br * 32 + ((q ^ (br & 3)) << 3)];
    }
#pragma unroll
    for (int fm = 0; fm < 2; ++fm)
#pragma unroll
      for (int fn = 0; fn < 4; ++fn)
        acc[fm][fn] = __builtin_amdgcn_mfma_f32_16x16x32_bf16(af[fm], bf[fn], acc[fm][fn], 0, 0, 0);
    __syncthreads();
  }

#pragma unroll
  for (int fn = 0; fn < 4; ++fn) {
    const int col = bn * 128 + wn * 64 + fn * 16 + r16;
    const float bv = bias[col];
#pragma unroll
    for (int fm = 0; fm < 2; ++fm) {
#pragma unroll
      for (int rr = 0; rr < 4; ++rr) {
        const int crow = bm * 64 + wm * 32 + fm * 16 + q * 4 + rr;
        C[(size_t)crow * ldc + col] = f2bf(fast_tanh(acc[fm][fn][rr] + bv));
      }
    }
  }
}

// ---------------- head: value + action from H2 ----------------
__global__ __launch_bounds__(256) void head_kernel(
    const short* __restrict__ H2, const float* __restrict__ W3p,
    const float* __restrict__ b3p, const float* __restrict__ W3v,
    const float* __restrict__ b3v, float* __restrict__ out)
{
  const int t = threadIdx.x, w = t >> 6, l = t & 63;
  const int row = blockIdx.x * 4 + w;
  const short* __restrict__ h = H2 + (size_t)row * 512;
  float vp0 = 0.f, vp1 = 0.f, vv = 0.f;
#pragma unroll
  for (int i = 0; i < 4; ++i) {
    const int k = i * 64 + l;
    const float hp = bf2f(h[k]);
    const float hv = bf2f(h[256 + k]);
    vp0 += hp * W3p[k * 4 + 0];
    vp1 += hp * W3p[k * 4 + 1];
    vv += hv * W3v[k];
  }
#pragma unroll
  for (int d = 1; d < 64; d <<= 1) {
    vp0 += __shfl_xor(vp0, d);
    vp1 += __shfl_xor(vp1, d);
    vv += __shfl_xor(vv, d);
  }
  if (l == 0) {
    float* __restrict__ orow = out + (size_t)row * OUT_STRIDE;
    orow[0] = vv + b3v[0];
    orow[1] = fast_tanh(vp0 + b3p[0]);
    orow[2] = fast_tanh(vp1 + b3p[1]);
  }
}

extern "C" void kernel_launch(void* const* d_in, const int* in_sizes, int n_in,
                              void* d_out, int out_size, void* d_ws, size_t ws_size,
                              hipStream_t stream) {
  (void)in_sizes; (void)n_in; (void)out_size; (void)ws_size;
  const float* inp   = (const float*)d_in[0];
  const float* W_emb = (const float*)d_in[1];
  const float* b_emb = (const float*)d_in[2];
  const float* Uq    = (const float*)d_in[3];
  const float* Ur    = (const float*)d_in[4];
  const float* Ua    = (const float*)d_in[5];
  const float* W1p   = (const float*)d_in[6];
  const float* b1p   = (const float*)d_in[7];
  const float* W2p   = (const float*)d_in[8];
  const float* b2p   = (const float*)d_in[9];
  const float* W3p   = (const float*)d_in[10];
  const float* b3p   = (const float*)d_in[11];
  const float* W1v   = (const float*)d_in[12];
  const float* b1v   = (const float*)d_in[13];
  const float* W2v   = (const float*)d_in[14];
  const float* b2v   = (const float*)d_in[15];
  const float* W3v   = (const float*)d_in[16];
  const float* b3v   = (const float*)d_in[17];

  char* ws = (char*)d_ws;
  float* WqF     = (float*)(ws + 0);        // 64x256 f32
  short* WembUrT = (short*)(ws + 65536);    // 256x64 bf16 (transposed)
  float* WembF   = (float*)(ws + 98304);    // 64x256 f32 (1/SC folded)
  float* bUq2    = (float*)(ws + 163840);   // 256 f32 (SC folded)
  float* bUr2    = (float*)(ws + 164864);   // 256 f32 (SC folded)
  float* Ua2     = (float*)(ws + 165888);   // 256 f32 (-2*Ua)
  float* sumUa   = (float*)(ws + 166912);   // 1 f32 (padded)
  float* b1cat   = (float*)(ws + 167168);   // 512 f32
  float* b2cat   = (float*)(ws + 169216);   // 512 f32
  short* W1T     = (short*)(ws + 171264);   // 512x320 bf16
  short* W2T     = (short*)(ws + 498944);   // 512x256 bf16
  short* state   = (short*)(ws + 761088);   // 4096x320 bf16
  short* H1      = (short*)(ws + 3382528);  // 4096x512 bf16
  short* H2      = (short*)(ws + 7576832);  // 4096x512 bf16

  prep_kernel<<<dim3(1282), dim3(256), 0, stream>>>(
      W_emb, b_emb, Uq, Ur, Ua, W1p, W1v, W2p, W2v, b1p, b1v, b2p, b2v,
      WqF, WembUrT, WembF, bUq2, bUr2, Ua2, sumUa, b1cat, b2cat, W1T, W2T);

  attn_kernel<<<dim3(4096), dim3(256), 0, stream>>>(
      inp, WembUrT, WqF, WembF, bUq2, bUr2, Ua2, sumUa, b_emb,
      (float*)d_out, state);

  mlp_gemm<<<dim3(64, 4), dim3(256), 0, stream>>>(state, 320, W1T, b1cat, H1, 512, 320, 0);
  mlp_gemm<<<dim3(64, 4), dim3(256), 0, stream>>>(H1, 512, W2T, b2cat, H2, 512, 256, 1);

  head_kernel<<<dim3(1024), dim3(256), 0, stream>>>(H2, W3p, b3p, W3v, b3v, (float*)d_out);
}